// Round 2
// baseline (245.155 us; speedup 1.0000x reference)
//
#include <hip/hip_runtime.h>
#include <hip/hip_bf16.h>
#include <math.h>

#define NQ 8192   // queries
#define MK 8192   // keys
#define CD 512    // embed dim
#define LN 64     // neighbors per query
#define HH 8      // heads
#define HD 64     // head dim
#define BB 16     // batches

typedef short short8 __attribute__((ext_vector_type(8)));
typedef float floatx4 __attribute__((ext_vector_type(4)));

// fp32 -> bf16 RNE scalar
__device__ __forceinline__ unsigned short f2bf(float x) {
    unsigned int u = __builtin_bit_cast(unsigned int, x);
    return (unsigned short)((u + 0x7FFFu + ((u >> 16) & 1u)) >> 16);
}
// packed pair via HW v_cvt_pk_bf16_f32 on gfx950
__device__ __forceinline__ unsigned int pkbf(float lo, float hi) {
    float2 f; f.x = lo; f.y = hi;
    __hip_bfloat162 h2 = __float22bfloat162_rn(f);
    unsigned int u;
    __builtin_memcpy(&u, &h2, 4);
    return u;
}
// bf16 pair low element -> float (exact)
__device__ __forceinline__ float bflo(unsigned int u) {
    return __builtin_bit_cast(float, u << 16);
}
// bf16 pair high element -> float WITH low-half junk bits: hi*(1+d),
// |d| <= 2^-8 — below bf16's own rounding noise; saves the mask op.
__device__ __forceinline__ float bfhij(unsigned int u) {
    return __builtin_bit_cast(float, u);
}
__device__ __forceinline__ short8 u4s8(uint4 u) {
    short8 s; __builtin_memcpy(&s, &u, 16); return s;
}
// bare transcendentals (avoid ocml range-fixup paths)
__device__ __forceinline__ float exp2v(float x) {
    float r; asm("v_exp_f32 %0, %1" : "=v"(r) : "v"(x)); return r;
}
__device__ __forceinline__ float rcpv(float x) {
    float r; asm("v_rcp_f32 %0, %1" : "=v"(r) : "v"(x)); return r;
}

// async global->LDS, 16B per lane; LDS dest = wave-uniform base + lane*16
__device__ __forceinline__ void gl_lds16(const unsigned short* g, unsigned short* l) {
    __builtin_amdgcn_global_load_lds(
        (const __attribute__((address_space(1))) unsigned int*)g,
        (__attribute__((address_space(3))) unsigned int*)l, 16, 0, 0);
}

// ---------------------------------------------------------------------------
// fp32 -> bf16 conversion prepass (5 segments in one launch)
// ---------------------------------------------------------------------------
struct ConvSeg { const float* src; unsigned short* dst; int n4; };
struct ConvArgs { ConvSeg s[5]; };

__global__ __launch_bounds__(256) void convert_bf16(ConvArgs a) {
    const int seg = blockIdx.y;
    const int i = blockIdx.x * 256 + threadIdx.x;
    if (i >= a.s[seg].n4) return;
    const float4 v = ((const float4*)a.s[seg].src)[i];
    uint2 o; o.x = pkbf(v.x, v.y); o.y = pkbf(v.z, v.w);
    ((uint2*)a.s[seg].dst)[i] = o;
}

// ---------------------------------------------------------------------------
// m97-style bf16 NT GEMM, 64x128 tile. BK=64, 256 threads = 4 waves.
// Staging via global_load_lds_dwordx4 with XOR-swizzled source granule
// (LDS[row][p] = A[row][p ^ (row&7)]) -> conflict-free ds_read_b128.
// ---------------------------------------------------------------------------
__device__ __forceinline__ void gemm_bf_body(const unsigned short* __restrict__ A,
                                             const unsigned short* __restrict__ W,
                                             const float* __restrict__ bias,
                                             float* __restrict__ outf,
                                             unsigned short* __restrict__ outb,
                                             float scale) {
    __shared__ unsigned short As[64 * 64];     // 8 KB
    __shared__ unsigned short Bs[128 * 64];    // 16 KB

    const int tid  = threadIdx.x;
    const int row0 = blockIdx.x * 64;
    const int col0 = blockIdx.y * 128;

    const int w    = tid >> 6;
    const int lane = tid & 63;
    const int q    = lane >> 4;    // quad
    const int ml   = lane & 15;

    const int sr = lane >> 3;            // 0..7 (== row&7 of the loaded row)
    const int sg = (lane & 7) ^ sr;      // XOR-swizzled source granule
    const unsigned short* Ap = A + (size_t)(row0 + w * 16 + sr) * CD + sg * 8;
    const unsigned short* Wp = W + (size_t)(col0 + w * 32 + sr) * CD + sg * 8;
    unsigned short* Asw = &As[(w * 16) * 64];
    unsigned short* Bsw = &Bs[(w * 32) * 64];

    floatx4 acc[4][2];
#pragma unroll
    for (int i = 0; i < 4; ++i)
#pragma unroll
        for (int j = 0; j < 2; ++j)
            acc[i][j] = (floatx4){0.f, 0.f, 0.f, 0.f};

    for (int k0 = 0; k0 < CD; k0 += 64) {
        __syncthreads();
#pragma unroll
        for (int i = 0; i < 2; ++i)
            gl_lds16(Ap + (size_t)(i * 8) * CD + k0, Asw + i * 8 * 64);
#pragma unroll
        for (int i = 0; i < 4; ++i)
            gl_lds16(Wp + (size_t)(i * 8) * CD + k0, Bsw + i * 8 * 64);
        __syncthreads();

#pragma unroll
        for (int kw = 0; kw < 2; ++kw) {
            short8 af[4], bf[2];
            const int gp = ((kw * 4 + q) ^ (ml & 7)) * 8;
#pragma unroll
            for (int mi = 0; mi < 4; ++mi)
                af[mi] = *(const short8*)&As[(mi * 16 + ml) * 64 + gp];
#pragma unroll
            for (int ni = 0; ni < 2; ++ni)
                bf[ni] = *(const short8*)&Bs[(w * 32 + ni * 16 + ml) * 64 + gp];
#pragma unroll
            for (int mi = 0; mi < 4; ++mi)
#pragma unroll
                for (int ni = 0; ni < 2; ++ni)
                    acc[mi][ni] = __builtin_amdgcn_mfma_f32_16x16x32_bf16(
                        af[mi], bf[ni], acc[mi][ni], 0, 0, 0);
        }
    }

    float bv[2];
#pragma unroll
    for (int ni = 0; ni < 2; ++ni)
        bv[ni] = bias[col0 + w * 32 + ni * 16 + ml];
#pragma unroll
    for (int mi = 0; mi < 4; ++mi) {
#pragma unroll
        for (int ni = 0; ni < 2; ++ni) {
            const int cg = col0 + w * 32 + ni * 16 + ml;
#pragma unroll
            for (int rr = 0; rr < 4; ++rr) {
                const int rg = row0 + mi * 16 + q * 4 + rr;
                const float val = (acc[mi][ni][rr] + bv[ni]) * scale;
                if (outb) outb[(size_t)rg * CD + cg] = f2bf(val);
                else      outf[(size_t)rg * CD + cg] = val;
            }
        }
    }
}

// qkv: z=0 -> q bf16 (scale 0.125*log2e folded pre-round: scores come out in
// log2 domain so softmax uses bare v_exp_f32); z=1 -> k; z=2 -> v
#define QSCALE 0.18033688011112042f   // 0.125 * log2(e)

__global__ __launch_bounds__(256) void qkv_gemm(const unsigned short* __restrict__ A_bf,
                                                const unsigned short* __restrict__ w_bf,
                                                const float* __restrict__ bias,
                                                unsigned short* __restrict__ q_bf,
                                                unsigned short* __restrict__ k_bf,
                                                unsigned short* __restrict__ v_bf) {
    const int z = blockIdx.z;
    const unsigned short* A = A_bf + (size_t)z * NQ * CD;
    unsigned short* outb = (z == 0) ? q_bf : ((z == 1) ? k_bf : v_bf);
    gemm_bf_body(A, w_bf + (size_t)z * CD * CD, bias + (size_t)z * CD,
                 nullptr, outb, (z == 0) ? QSCALE : 1.0f);
}

__global__ __launch_bounds__(256) void out_gemm(const unsigned short* __restrict__ A,
                                                const unsigned short* __restrict__ W,
                                                const float* __restrict__ bias,
                                                float* __restrict__ out) {
    gemm_bf_body(A, W, bias, out, nullptr, 1.0f);
}

// PV inner: 8 fma, acc[d] covers dims lane*8+d
__device__ __forceinline__ void fma8(float (&a)[8], uint4 u, float w) {
    a[0] = fmaf(w, bflo(u.x),  a[0]);
    a[1] = fmaf(w, bfhij(u.x), a[1]);
    a[2] = fmaf(w, bflo(u.y),  a[2]);
    a[3] = fmaf(w, bfhij(u.y), a[3]);
    a[4] = fmaf(w, bflo(u.z),  a[4]);
    a[5] = fmaf(w, bfhij(u.z), a[5]);
    a[6] = fmaf(w, bflo(u.w),  a[6]);
    a[7] = fmaf(w, bfhij(u.w), a[7]);
}

// ---------------------------------------------------------------------------
// Attention (R10 resubmit): one wave = one query, zero barriers.
// Scores: MFMA with q broadcast across B columns => EVERY lane already holds
// the 16 scores of its quad's neighbors (sa[grp][rr] = neighbor
// grp*16+quad*4+rr). Softmax is a local 15-op tree + 2 shfl_xor (quad bits)
// per reduce — no LDS publish round-trip, no 12-shfl butterfly. q pre-scaled
// by log2e so exp is bare v_exp_f32. Each lane publishes exactly one
// normalized weight (bijection lane->neighbor) to a wave-private LDS strip
// w_s[head][64] (stride 68: conflict-free b128 reads).
// PV: lane owns dims lane*8..+7 (all heads at once); per neighbor the row id
// is broadcast to an SGPR via readlane -> one fully-coalesced 1KB row load +
// one ds_read of w + 8 fma. No shfl at all in PV; output store is a
// coalesced uint4. k/q fragments and PV rows are 2-deep prefetch-pipelined.
// ---------------------------------------------------------------------------
__global__ __launch_bounds__(256) void attn_kernel(
    const unsigned short* __restrict__ q_bf,     // NQ*CD bf16 (log2e-scaled)
    const unsigned short* __restrict__ k_bf,     // NQ*CD bf16
    const unsigned short* __restrict__ v_bf,     // NQ*CD bf16
    const int* __restrict__ index_pair,          // (NQ, LN)
    const int* __restrict__ key_batch_cnt,       // (BB,)
    const int* __restrict__ index_pair_batch,    // (NQ,)
    unsigned short* __restrict__ attn_bf,        // NQ*CD bf16
    float* __restrict__ out2) {                  // NQ*LN
    const int tid  = threadIdx.x;
    const int wid  = tid >> 6;
    const int lane = tid & 63;
    const int bx   = blockIdx.x;
    const int n    = (bx & 7) * (NQ / 8) + (bx >> 3) * 4 + wid;   // XCD swizzle

    const int quad = lane >> 4;    // 0..3
    const int ml   = lane & 15;

    __shared__ float w_s[4][HH][68];     // 8.5 KB; stride 68 => b128 conflict-free
    float* ws = &w_s[wid][0][0];

    // key offset via parallel prefix scan (lanes 0..15)
    int cnt = (lane < BB) ? key_batch_cnt[lane] : 0;
#pragma unroll
    for (int d = 1; d < BB; d <<= 1) {
        const int t = __shfl_up(cnt, d, 64);
        if (lane >= d) cnt += t;
    }
    const int batch = index_pair_batch[n];
    const int off0  = (batch > 0) ? __shfl(cnt, batch - 1, 64) : 0;

    // gather indices: lane = neighbor
    const int gi = index_pair[n * LN + lane];
    const unsigned long long vmask = __ballot(gi >= 0);
    const int g = (gi >= 0) ? (gi + off0) : 0;   // reference safe-gather

    // rows for the MFMA A-frag (k): A row ml of group grp = neighbor grp*16+ml
    int krow[4];
#pragma unroll
    for (int grp = 0; grp < 4; ++grp)
        krow[grp] = __shfl(g, grp * 16 + ml, 64);

    // per-lane validity bits for its 16 (grp,rr) score slots (hoisted)
    const unsigned long long tb = vmask >> (quad * 4);
    const unsigned mybits =
        (unsigned)( (tb & 0xFull)
                  | (((tb >> 16) & 0xFull) << 4)
                  | (((tb >> 32) & 0xFull) << 8)
                  | (((tb >> 48) & 0xFull) << 12));
    bool bc[16];
#pragma unroll
    for (int i = 0; i < 16; ++i) bc[i] = (mybits >> i) & 1u;
    const bool p0 = ml & 1, p1 = ml & 2, p2 = ml & 4, p3 = ml & 8;
    const int jpub = (ml >> 2) * 16 + quad * 4 + (ml & 3);  // lane->neighbor bijection

    // hoisted base pointers: per-head k/q loads become literal-offset loads
    const char* qp = (const char*)(q_bf + (size_t)n * CD) + quad * 16;
    const char* kp[4];
#pragma unroll
    for (int grp = 0; grp < 4; ++grp)
        kp[grp] = (const char*)(k_bf + (size_t)krow[grp] * CD) + quad * 16;

    // ---- phase A: scores + softmax per head, 2-deep prefetch pipeline ----
    uint4 ka[2][8], qa[2][2];
#pragma unroll
    for (int grp = 0; grp < 4; ++grp) {
        ka[0][grp * 2]     = *(const uint4*)(kp[grp]);
        ka[0][grp * 2 + 1] = *(const uint4*)(kp[grp] + 64);
    }
    qa[0][0] = *(const uint4*)(qp);
    qa[0][1] = *(const uint4*)(qp + 64);

#pragma unroll
    for (int h = 0; h < HH; ++h) {
        const int cb = h & 1;
        if (h < HH - 1) {       // prefetch next head's fragments
#pragma unroll
            for (int grp = 0; grp < 4; ++grp) {
                ka[cb ^ 1][grp * 2]     = *(const uint4*)(kp[grp] + (h + 1) * 128);
                ka[cb ^ 1][grp * 2 + 1] = *(const uint4*)(kp[grp] + (h + 1) * 128 + 64);
            }
            qa[cb ^ 1][0] = *(const uint4*)(qp + (h + 1) * 128);
            qa[cb ^ 1][1] = *(const uint4*)(qp + (h + 1) * 128 + 64);
        }

        floatx4 sa[4];
#pragma unroll
        for (int grp = 0; grp < 4; ++grp) {
            floatx4 z = (floatx4){0.f, 0.f, 0.f, 0.f};
            z = __builtin_amdgcn_mfma_f32_16x16x32_bf16(u4s8(ka[cb][grp * 2]),
                                                        u4s8(qa[cb][0]), z, 0, 0, 0);
            z = __builtin_amdgcn_mfma_f32_16x16x32_bf16(u4s8(ka[cb][grp * 2 + 1]),
                                                        u4s8(qa[cb][1]), z, 0, 0, 0);
            sa[grp] = z;
        }

        // mask (log2-domain scores; MASK_VAL semantics preserved)
        float sc[16];
#pragma unroll
        for (int grp = 0; grp < 4; ++grp)
#pragma unroll
            for (int rr = 0; rr < 4; ++rr)
                sc[grp * 4 + rr] = bc[grp * 4 + rr] ? sa[grp][rr] : -1000.0f;

        // max: 15-op local tree + 2 shfl over quad bits
        float m8[8];
#pragma unroll
        for (int i = 0; i < 8; ++i) m8[i] = fmaxf(sc[2 * i], sc[2 * i + 1]);
        float mx = fmaxf(fmaxf(fmaxf(m8[0], m8[1]), fmaxf(m8[2], m8[3])),
                         fmaxf(fmaxf(m8[4], m8[5]), fmaxf(m8[6], m8[7])));
        mx = fmaxf(mx, __shfl_xor(mx, 16, 64));
        mx = fmaxf(mx, __shfl_xor(mx, 32, 64));

        // exp2 + sum tree + 2 shfl
        float e[16];
#pragma unroll
        for (int i = 0; i < 16; ++i) e[i] = exp2v(sc[i] - mx);
        float s4[8];
#pragma unroll
        for (int i = 0; i < 8; ++i) s4[i] = e[2 * i] + e[2 * i + 1];
        float s = ((s4[0] + s4[1]) + (s4[2] + s4[3])) + ((s4[4] + s4[5]) + (s4[6] + s4[7]));
        s += __shfl_xor(s, 16, 64);
        s += __shfl_xor(s, 32, 64);
        const float rs = rcpv(s);

        // pick e[ml] via 15-cndmask tree (selectors hoisted), publish w
        float t4[4];
#pragma unroll
        for (int gsel = 0; gsel < 4; ++gsel) {
            const float e01 = p0 ? e[gsel * 4 + 1] : e[gsel * 4 + 0];
            const float e23 = p0 ? e[gsel * 4 + 3] : e[gsel * 4 + 2];
            t4[gsel] = p1 ? e23 : e01;
        }
        const float u0 = p2 ? t4[1] : t4[0];
        const float u1 = p2 ? t4[3] : t4[2];
        const float pick = p3 ? u1 : u0;
        ws[h * 68 + jpub] = pick * rs;          // 64 distinct j -> 2-way free
    }

    // ---- phase B: PV, lane = 8 dims across all heads, 2-deep row pipeline --
    float acc[8] = {0.f, 0.f, 0.f, 0.f, 0.f, 0.f, 0.f, 0.f};
    const float* wrow = ws + (lane >> 3) * 68;   // this lane's head row
    uint4 vr[2][8];
#pragma unroll
    for (int i = 0; i < 8; ++i) {
        const int row = __builtin_amdgcn_readlane(g, i);          // SGPR row id
        vr[0][i] = *(const uint4*)(v_bf + (size_t)row * CD + (lane << 3));
    }
#pragma unroll
    for (int c = 0; c < 8; ++c) {
        const int cb = c & 1;
        if (c < 7) {
#pragma unroll
            for (int i = 0; i < 8; ++i) {
                const int row = __builtin_amdgcn_readlane(g, (c + 1) * 8 + i);
                vr[cb ^ 1][i] = *(const uint4*)(v_bf + (size_t)row * CD + (lane << 3));
            }
        }
        const float4 w0 = *(const float4*)(wrow + c * 8);       // ds_read_b128
        const float4 w1 = *(const float4*)(wrow + c * 8 + 4);   // conflict-free
        fma8(acc, vr[cb][0], w0.x); fma8(acc, vr[cb][1], w0.y);
        fma8(acc, vr[cb][2], w0.z); fma8(acc, vr[cb][3], w0.w);
        fma8(acc, vr[cb][4], w1.x); fma8(acc, vr[cb][5], w1.y);
        fma8(acc, vr[cb][6], w1.z); fma8(acc, vr[cb][7], w1.w);
    }

    // coalesced bf16 store: lane writes dims lane*8..+7
    uint4 o;
    o.x = pkbf(acc[0], acc[1]); o.y = pkbf(acc[2], acc[3]);
    o.z = pkbf(acc[4], acc[5]); o.w = pkbf(acc[6], acc[7]);
    *(uint4*)(attn_bf + (size_t)n * CD + (lane << 3)) = o;

    // output 2: sum over heads / H, straight from the LDS strip
    float s8 = 0.f;
#pragma unroll
    for (int h = 0; h < HH; ++h) s8 += ws[h * 68 + lane];
    out2[(size_t)n * LN + lane] = s8 * (1.0f / HH);
}

// ---------------------------------------------------------------------------
extern "C" void kernel_launch(void* const* d_in, const int* in_sizes, int n_in,
                              void* d_out, int out_size, void* d_ws, size_t ws_size,
                              hipStream_t stream) {
    const float* query   = (const float*)d_in[0];
    const float* key     = (const float*)d_in[1];
    const float* value   = (const float*)d_in[2];
    const float* ipw     = (const float*)d_in[3];   // (3C, C)
    const float* ipb     = (const float*)d_in[4];   // (3C,)
    const float* out_w   = (const float*)d_in[5];   // (C, C)
    const float* out_b   = (const float*)d_in[6];   // (C,)
    const int*   index_pair       = (const int*)d_in[7];
    // d_in[8] = query_batch_cnt (unused: implied by index_pair_batch)
    const int*   key_batch_cnt    = (const int*)d_in[9];
    const int*   index_pair_batch = (const int*)d_in[10];

    float* out = (float*)d_out;                // [attn (NQ*CD) | out2 (NQ*LN)]
    // ws layout (bf16): q 8MB | k 8 | v 8 | A_in 24 | ipw 3 | out_w 1
    unsigned short* q_bf  = (unsigned short*)d_ws;
    unsigned short* k_bf  = q_bf + (size_t)NQ * CD;
    unsigned short* v_bf  = k_bf + (size_t)NQ * CD;
    unsigned short* A_bf  = v_bf + (size_t)NQ * CD;        // 3 * NQ*CD
    unsigned short* w_bf  = A_bf + (size_t)3 * NQ * CD;    // 3 * CD*CD (ipw)
    unsigned short* ow_bf = w_bf + (size_t)3 * CD * CD;    // CD*CD (out_w)
    // attn output (bf16) reuses the A_bf query slot (qkv_gemm done with it)
    unsigned short* attn_bf = A_bf;

    // 0) convert inputs/weights to bf16
    ConvArgs ca;
    ca.s[0] = {query, A_bf,                       NQ * CD / 4};
    ca.s[1] = {key,   A_bf + (size_t)NQ * CD,     NQ * CD / 4};
    ca.s[2] = {value, A_bf + (size_t)2 * NQ * CD, NQ * CD / 4};
    ca.s[3] = {ipw,   w_bf,                       3 * CD * CD / 4};
    ca.s[4] = {out_w, ow_bf,                      CD * CD / 4};
    dim3 g0(NQ * CD / 4 / 256, 5);
    convert_bf16<<<g0, 256, 0, stream>>>(ca);

    // 1) q/k/v projections (q pre-scaled by 0.125*log2e -> log2-domain scores)
    dim3 g1(NQ / 64, CD / 128, 3);
    qkv_gemm<<<g1, 256, 0, stream>>>(A_bf, w_bf, ipb, q_bf, k_bf, v_bf);

    // 2) gather attention -> bf16 attn + output 2
    attn_kernel<<<NQ / 4, 256, 0, stream>>>(q_bf, k_bf, v_bf, index_pair,
                                            key_batch_cnt, index_pair_batch,
                                            attn_bf, out + (size_t)NQ * CD);

    // 3) out projection -> output 1
    dim3 g3(NQ / 64, CD / 128, 1);
    out_gemm<<<g3, 256, 0, stream>>>(attn_bf, ow_bf, out_b, out);
}